// Round 5
// baseline (27524.115 us; speedup 1.0000x reference)
//
#include <hip/hip_runtime.h>

// TimeVAEDecoder: B=128, LAT=128, H=512, F=128, L=256, NL=2
// Round 5: PERSISTENT kernel. Rounds 3/4 showed ~25us/dispatch across 770
// serialized graph nodes (launch-overhead bound). This round: ONE kernel,
// 256 blocks x 256 thr (1 block/CU), 3 device-scope grid barriers per step.
// Numerics identical to round 4 (3-plane bf16 split, 6 MFMA products into
// 4 accumulators, two-pass LN) -> absmax pedigree 0.0703.
//  - cell state c lives in registers (block owns its (b,h) tile all steps)
//  - ys[t-1] on blocks 0..63 during phase A (s(t-1) stable there)
//  - grid barrier: monotonic counter, acq/rel agent-scope atomics

typedef unsigned int uint32;
typedef unsigned short u16;
typedef __attribute__((ext_vector_type(8))) short bf16x8;
typedef __attribute__((ext_vector_type(4))) float f32x4;

static constexpr int Ln = 256, Fn = 128;
static constexpr int APS = 65536;    // activation plane stride (elems): 128x512
static constexpr int WPS = 2097152;  // cell-weight plane stride: 2048x1024
static constexpr int OPS = 65536;    // W_out plane stride: 128x512
static constexpr int PPS = 262144;   // W_pre plane stride: 512x512

__device__ __forceinline__ u16 f2bf(float f) {
  union { float f; uint32 u; } v; v.f = f;
  uint32 u = v.u + 0x7fffu + ((v.u >> 16) & 1u);
  return (u16)(u >> 16);
}
__device__ __forceinline__ float bf2f(u16 h) {
  union { uint32 u; float f; } v; v.u = ((uint32)h) << 16;
  return v.f;
}
__device__ __forceinline__ void splitbf3(float v, u16* hi, u16* mid, u16* lo) {
  u16 h = f2bf(v);
  float r = v - bf2f(h);
  u16 m = f2bf(r);
  float r2 = r - bf2f(m);
  *hi = h; *mid = m; *lo = f2bf(r2);
}
__device__ __forceinline__ float sigm(float x) { return 1.f / (1.f + expf(-x)); }
__device__ __forceinline__ bf16x8 ldf(const u16* p) { return *(const bf16x8*)p; }

#define MFMA1(A, B, ACC) ACC = __builtin_amdgcn_mfma_f32_16x16x32_bf16((A), (B), (ACC), 0, 0, 0)
// 6 products, 4 accumulators: A0+=hh; A1+=hm+mh; A2+=hl+mm; A3+=lh
#define MFMA6(AH, AM, AL, BH, BM, BL, A0, A1, A2, A3) \
  do {                                                \
    MFMA1(AH, BH, A0);                                \
    MFMA1(AH, BM, A1); MFMA1(AM, BH, A1);             \
    MFMA1(AH, BL, A2); MFMA1(AM, BM, A2);             \
    MFMA1(AL, BH, A3);                                \
  } while (0)

// ---------------- prep kernels ----------------

__global__ void prep_hc0(const float* __restrict__ z,
                         const float* __restrict__ W_l2h, const float* __restrict__ b_l2h,
                         const float* __restrict__ W_l2c, const float* __restrict__ b_l2c,
                         u16* __restrict__ ha0, u16* __restrict__ hb0,
                         float* __restrict__ ca, float* __restrict__ cb) {
  int idx = blockIdx.x * 256 + threadIdx.x;  // 131072
  int b = idx & 127, j = idx >> 7;
  float ah = b_l2h[j], ac = b_l2c[j];
  for (int k = 0; k < 128; ++k) {
    float zv = z[b * 128 + k];
    ah += zv * W_l2h[j * 128 + k];
    ac += zv * W_l2c[j * 128 + k];
  }
  int flat = b * 1024 + j;
  if (flat < 65536) {
    splitbf3(ah, &ha0[flat], &ha0[APS + flat], &ha0[2 * APS + flat]);
    ca[flat] = ac;
  } else {
    flat -= 65536;
    splitbf3(ah, &hb0[flat], &hb0[APS + flat], &hb0[2 * APS + flat]);
    cb[flat] = ac;
  }
}

__global__ void prep_zp(const float* __restrict__ z, const float* __restrict__ W_zp,
                        const float* __restrict__ b_zp, float* __restrict__ zp) {
  int idx = blockIdx.x * 256 + threadIdx.x;  // 65536
  int b = idx & 127, h = idx >> 7;
  float a = b_zp[h];
  for (int k = 0; k < 128; ++k) a += z[b * 128 + k] * W_zp[h * 128 + k];
  zp[b * 512 + h] = a;
}

__global__ void prep_gz(const float* __restrict__ zp, const float* __restrict__ W_ih0,
                        const float* __restrict__ b_ih0, const float* __restrict__ b_hh0,
                        const float* __restrict__ b_out,
                        float* __restrict__ GZ0, float* __restrict__ GZ1) {
  int idx = blockIdx.x * 256 + threadIdx.x;  // 262144
  int b = idx & 127, g = idx >> 7;
  const float* wr = W_ih0 + (size_t)g * 640;
  float a = b_ih0[g] + b_hh0[g];
  for (int k = 0; k < 512; ++k) a += zp[b * 512 + k] * wr[128 + k];
  float co = 0.f;
  for (int f = 0; f < 128; ++f) co += b_out[f] * wr[f];
  GZ0[b * 2048 + g] = a;
  GZ1[b * 2048 + g] = a + co;
}

__global__ void prep_waf(const float* __restrict__ W_out, const float* __restrict__ W_ih0,
                         const float* __restrict__ W_hh0, u16* __restrict__ WAf) {
  int idx = blockIdx.x * 256 + threadIdx.x;  // 2097152
  int k = idx & 1023, g = idx >> 10;
  float v;
  if (k < 512) {
    v = 0.f;
    const float* wr = W_ih0 + (size_t)g * 640;
    for (int f = 0; f < 128; ++f) v += W_out[f * 512 + k] * wr[f];
  } else {
    v = W_hh0[(size_t)g * 512 + (k - 512)];
  }
  splitbf3(v, &WAf[idx], &WAf[WPS + idx], &WAf[2 * WPS + idx]);
}

__global__ void prep_wbf(const float* __restrict__ W_ih1, const float* __restrict__ W_hh1,
                         u16* __restrict__ WBf) {
  int idx = blockIdx.x * 256 + threadIdx.x;  // 2097152
  int k = idx & 1023, g = idx >> 10;
  float v = (k < 512) ? W_ih1[(size_t)g * 512 + k] : W_hh1[(size_t)g * 512 + (k - 512)];
  splitbf3(v, &WBf[idx], &WBf[WPS + idx], &WBf[2 * WPS + idx]);
}

__global__ void prep_misc(const float* __restrict__ W_pre, const float* __restrict__ W_out,
                          const float* __restrict__ b_ih1, const float* __restrict__ b_hh1,
                          u16* __restrict__ WPf, u16* __restrict__ WOf,
                          float* __restrict__ gb1, u16* __restrict__ s,
                          uint32* __restrict__ barcnt) {
  int idx = blockIdx.x * 256 + threadIdx.x;  // 526344 total
  if (idx < 262144) { splitbf3(W_pre[idx], &WPf[idx], &WPf[PPS + idx], &WPf[2 * PPS + idx]); return; }
  idx -= 262144;
  if (idx < 65536) { splitbf3(W_out[idx], &WOf[idx], &WOf[OPS + idx], &WOf[2 * OPS + idx]); return; }
  idx -= 65536;
  if (idx < 2048) { gb1[idx] = b_ih1[idx] + b_hh1[idx]; return; }
  idx -= 2048;
  if (idx < 196608) { s[idx] = 0; return; }  // all 3 planes of s
  idx -= 196608;
  if (idx < 8) barcnt[idx] = 0;
}

// ---------------- persistent kernel ----------------

__device__ __forceinline__ void gridbar(uint32* cnt, int tid) {
  __syncthreads();
  if (tid == 0) {
    uint32 old = __hip_atomic_fetch_add(cnt, 1u, __ATOMIC_ACQ_REL, __HIP_MEMORY_SCOPE_AGENT);
    uint32 target = (old / 256u + 1u) * 256u;
    while (__hip_atomic_load(cnt, __ATOMIC_ACQUIRE, __HIP_MEMORY_SCOPE_AGENT) < target)
      __builtin_amdgcn_s_sleep(8);
  }
  __syncthreads();
}

// LSTM cell gate unit (round-3 structure, round-4 accumulators): M=16 rows,
// 4 waves = 4 gates x 16 h-cols, K=1024 = [x0 || x1]. c state in register.
__device__ __forceinline__ void gates_unit(
    const u16* __restrict__ x0, const u16* __restrict__ x1,
    const u16* __restrict__ Wf, const float* __restrict__ bias, int bias_stride,
    float& creg, u16* __restrict__ hout,
    int hg, int mg, int tid, float (*gbuf)[16][17]) {
  int lane = tid & 63, w = tid >> 6;
  int q = lane >> 4, r16 = lane & 15;
  const u16* wr = Wf + (size_t)(w * 512 + hg * 16 + r16) * 1024 + q * 8;
  const u16* a0 = x0 + (size_t)(mg * 16 + r16) * 512 + q * 8;
  const u16* a1 = x1 + (size_t)(mg * 16 + r16) * 512 + q * 8;
  f32x4 A0 = {0.f, 0.f, 0.f, 0.f}, A1 = A0, A2 = A0, A3 = A0;
#pragma unroll 8
  for (int kb = 0; kb < 16; ++kb) {
    bf16x8 ah = ldf(a0 + kb * 32), am = ldf(a0 + APS + kb * 32), al = ldf(a0 + 2 * APS + kb * 32);
    bf16x8 bh = ldf(wr + kb * 32), bm = ldf(wr + WPS + kb * 32), bl = ldf(wr + 2 * WPS + kb * 32);
    MFMA6(ah, am, al, bh, bm, bl, A0, A1, A2, A3);
  }
#pragma unroll 8
  for (int kb = 0; kb < 16; ++kb) {
    bf16x8 ah = ldf(a1 + kb * 32), am = ldf(a1 + APS + kb * 32), al = ldf(a1 + 2 * APS + kb * 32);
    bf16x8 bh = ldf(wr + 512 + kb * 32), bm = ldf(wr + WPS + 512 + kb * 32),
           bl = ldf(wr + 2 * WPS + 512 + kb * 32);
    MFMA6(ah, am, al, bh, bm, bl, A0, A1, A2, A3);
  }
#pragma unroll
  for (int r = 0; r < 4; ++r)
    gbuf[w][q * 4 + r][r16] = ((A3[r] + A2[r]) + A1[r]) + A0[r];
  __syncthreads();
  int bl_ = tid >> 4, hl = tid & 15;
  int b = mg * 16 + bl_, h = hg * 16 + hl;
  const float* bb = bias + (size_t)b * bias_stride;  // 2048 (GZ) or 0 (gb1)
  float gi = gbuf[0][bl_][hl] + bb[h];
  float gf = gbuf[1][bl_][hl] + bb[512 + h];
  float gc = gbuf[2][bl_][hl] + bb[1024 + h];
  float go = gbuf[3][bl_][hl] + bb[1536 + h];
  float cn = sigm(gf) * creg + sigm(gi) * tanhf(gc);
  creg = cn;
  float hv = sigm(go) * tanhf(cn);
  int idx = b * 512 + h;
  splitbf3(hv, &hout[idx], &hout[APS + idx], &hout[2 * APS + idx]);
}

// ys tile: 16 rows x 16 f-cols, 4 waves split K=512 into 4x128, LDS reduce.
__device__ __forceinline__ void ys_unit(
    const u16* __restrict__ sv, const u16* __restrict__ WOf,
    const float* __restrict__ b_out, float* __restrict__ ys,
    int t, int bg, int fh, int tid, float (*gbuf)[16][17]) {
  int lane = tid & 63, w = tid >> 6;
  int q = lane >> 4, r16 = lane & 15;
  int f0 = fh * 16, b0 = bg * 16;
  const u16* wr = WOf + (size_t)(f0 + r16) * 512 + w * 128 + q * 8;
  const u16* ar = sv + (size_t)(b0 + r16) * 512 + w * 128 + q * 8;
  f32x4 A0 = {0.f, 0.f, 0.f, 0.f}, A1 = A0, A2 = A0, A3 = A0;
#pragma unroll
  for (int kb = 0; kb < 4; ++kb) {
    bf16x8 ah = ldf(ar + kb * 32), am = ldf(ar + APS + kb * 32), al = ldf(ar + 2 * APS + kb * 32);
    bf16x8 bh = ldf(wr + kb * 32), bm = ldf(wr + OPS + kb * 32), bl = ldf(wr + 2 * OPS + kb * 32);
    MFMA6(ah, am, al, bh, bm, bl, A0, A1, A2, A3);
  }
#pragma unroll
  for (int r = 0; r < 4; ++r)
    gbuf[w][q * 4 + r][r16] = ((A3[r] + A2[r]) + A1[r]) + A0[r];
  __syncthreads();
  int bl_ = tid >> 4, fl = tid & 15;
  float val = ((gbuf[3][bl_][fl] + gbuf[2][bl_][fl]) + gbuf[1][bl_][fl]) + gbuf[0][bl_][fl]
              + b_out[f0 + fl];
  ys[(size_t)(b0 + bl_) * (Ln * Fn) + (size_t)(t - 1) * Fn + f0 + fl] = val;
}

// LN(hb) -> pre = relu(ln@W_pre^T + b_pre) -> s = pre + ln  (round-4 body)
__device__ __forceinline__ void lnpre_unit(
    const u16* __restrict__ hb, const u16* __restrict__ WPf,
    const float* __restrict__ lng, const float* __restrict__ lnb,
    const float* __restrict__ b_pre, u16* __restrict__ s_out,
    int jg, int bg, int tid, float (*gbuf)[16][17],
    u16* lnH, u16* lnM, u16* lnL, float (*red)[16], float* smean, float* srstd) {
  int lane = tid & 63, w = tid >> 6;
  int q = lane >> 4, r16 = lane & 15;
  int j0 = jg * 16, b0 = bg * 16;
  int rl = tid >> 4, cg = tid & 15;
  float v[32];
  {
    const u16* hr = hb + (size_t)(b0 + rl) * 512 + cg * 32;
    float sm = 0.f;
#pragma unroll
    for (int kk = 0; kk < 32; ++kk) {
      v[kk] = (bf2f(hr[2 * APS + kk]) + bf2f(hr[APS + kk])) + bf2f(hr[kk]);
      sm += v[kk];
    }
    red[rl][cg] = sm;
  }
  __syncthreads();
  if (tid < 16) {
    float s1 = 0.f;
    for (int i = 0; i < 16; ++i) s1 += red[tid][i];
    smean[tid] = s1 * (1.f / 512.f);
  }
  __syncthreads();
  float m = smean[rl];
  {
    float sq = 0.f;
#pragma unroll
    for (int kk = 0; kk < 32; ++kk) { float d = v[kk] - m; sq += d * d; }
    red[rl][cg] = sq;
  }
  __syncthreads();
  if (tid < 16) {
    float s2 = 0.f;
    for (int i = 0; i < 16; ++i) s2 += red[tid][i];
    srstd[tid] = 1.f / sqrtf(s2 * (1.f / 512.f) + 1e-5f);
  }
  __syncthreads();
  float rs = srstd[rl];
#pragma unroll
  for (int kk = 0; kk < 32; ++kk) {
    int col = cg * 32 + kk;
    float lv = (v[kk] - m) * rs * lng[col] + lnb[col];
    splitbf3(lv, &lnH[rl * 520 + col], &lnM[rl * 520 + col], &lnL[rl * 520 + col]);
  }
  __syncthreads();
  const u16* wr = WPf + (size_t)(j0 + r16) * 512 + w * 128 + q * 8;
  const u16* aH = lnH + r16 * 520 + w * 128 + q * 8;
  const u16* aM = lnM + r16 * 520 + w * 128 + q * 8;
  const u16* aL = lnL + r16 * 520 + w * 128 + q * 8;
  f32x4 A0 = {0.f, 0.f, 0.f, 0.f}, A1 = A0, A2 = A0, A3 = A0;
#pragma unroll
  for (int kb = 0; kb < 4; ++kb) {
    bf16x8 ah = ldf(aH + kb * 32), am = ldf(aM + kb * 32), al = ldf(aL + kb * 32);
    bf16x8 bh = ldf(wr + kb * 32), bm = ldf(wr + PPS + kb * 32), bl = ldf(wr + 2 * PPS + kb * 32);
    MFMA6(ah, am, al, bh, bm, bl, A0, A1, A2, A3);
  }
#pragma unroll
  for (int r = 0; r < 4; ++r)
    gbuf[w][q * 4 + r][r16] = ((A3[r] + A2[r]) + A1[r]) + A0[r];
  __syncthreads();
  int bl_ = tid >> 4, jl = tid & 15;
  int col = j0 + jl;
  float pre = ((gbuf[3][bl_][jl] + gbuf[2][bl_][jl]) + gbuf[1][bl_][jl]) + gbuf[0][bl_][jl]
              + b_pre[col];
  pre = fmaxf(pre, 0.f);
  float lnv = (bf2f(lnL[bl_ * 520 + col]) + bf2f(lnM[bl_ * 520 + col])) + bf2f(lnH[bl_ * 520 + col]);
  float sval = pre + lnv;
  size_t sidx = (size_t)(b0 + bl_) * 512 + col;
  splitbf3(sval, &s_out[sidx], &s_out[APS + sidx], &s_out[2 * APS + sidx]);
}

__global__ __launch_bounds__(256, 1) void persist_k(
    const u16* __restrict__ WAf, const u16* __restrict__ WBf,
    const u16* __restrict__ WPf, const u16* __restrict__ WOf,
    const float* __restrict__ GZ0, const float* __restrict__ GZ1,
    const float* __restrict__ gb1,
    const float* __restrict__ ca, const float* __restrict__ cb,
    u16* ha0, u16* ha1, u16* hb0, u16* hb1, u16* sbuf,
    const float* __restrict__ lng, const float* __restrict__ lnb,
    const float* __restrict__ b_pre, const float* __restrict__ b_out,
    float* __restrict__ out, uint32* barcnt) {
  __shared__ float gbuf[4][16][17];
  __shared__ u16 lnH[16 * 520], lnM[16 * 520], lnL[16 * 520];
  __shared__ float red[16][16], smean[16], srstd[16];
  int tid = threadIdx.x, blk = blockIdx.x;
  int hg = blk & 31, mg = blk >> 5;  // gate-unit tile (hg fast -> XCD-local weights)
  int jg = blk & 31, bg = blk >> 5;  // lnpre tile
  int ys_bg = blk >> 3, ys_fh = blk & 7;  // ys tile for blk < 64
  // cell state in registers (this block owns these (b,h) every step)
  int bl_ = tid >> 4, hl = tid & 15;
  int cidx = (mg * 16 + bl_) * 512 + hg * 16 + hl;
  float creg_a = ca[cidx];
  float creg_b = cb[cidx];
  u16* haB[2] = {ha0, ha1};
  u16* hbB[2] = {hb0, hb1};
  for (int t = 0; t < Ln; ++t) {
    // phase A: gates0 from [s || ha]; blocks 0..63 also emit ys[t-1]
    gates_unit(sbuf, haB[t & 1], WAf, t ? GZ1 : GZ0, 2048, creg_a,
               haB[(t + 1) & 1], hg, mg, tid, gbuf);
    if (blk < 64 && t >= 1) {
      __syncthreads();  // gbuf reuse
      ys_unit(sbuf, WOf, b_out, out, t, ys_bg, ys_fh, tid, gbuf);
    }
    gridbar(barcnt, tid);
    // phase B: gates1 from [ha' || hb]
    gates_unit(haB[(t + 1) & 1], hbB[t & 1], WBf, gb1, 0, creg_b,
               hbB[(t + 1) & 1], hg, mg, tid, gbuf);
    gridbar(barcnt, tid);
    // phase C: layernorm + pre + s'
    lnpre_unit(hbB[(t + 1) & 1], WPf, lng, lnb, b_pre, sbuf,
               jg, bg, tid, gbuf, lnH, lnM, lnL, red, smean, srstd);
    gridbar(barcnt, tid);
  }
  if (blk < 64)
    ys_unit(sbuf, WOf, b_out, out, Ln, ys_bg, ys_fh, tid, gbuf);  // ys[L-1]
}

// ---------------- host ----------------

extern "C" void kernel_launch(void* const* d_in, const int* in_sizes, int n_in,
                              void* d_out, int out_size, void* d_ws, size_t ws_size,
                              hipStream_t stream) {
  const float* z     = (const float*)d_in[0];
  const float* W_l2h = (const float*)d_in[1];
  const float* b_l2h = (const float*)d_in[2];
  const float* W_l2c = (const float*)d_in[3];
  const float* b_l2c = (const float*)d_in[4];
  const float* W_zp  = (const float*)d_in[5];
  const float* b_zp  = (const float*)d_in[6];
  const float* W_ih0 = (const float*)d_in[7];
  const float* W_hh0 = (const float*)d_in[8];
  const float* b_ih0 = (const float*)d_in[9];
  const float* b_hh0 = (const float*)d_in[10];
  const float* W_ih1 = (const float*)d_in[11];
  const float* W_hh1 = (const float*)d_in[12];
  const float* b_ih1 = (const float*)d_in[13];
  const float* b_hh1 = (const float*)d_in[14];
  const float* ln_g  = (const float*)d_in[15];
  const float* ln_b  = (const float*)d_in[16];
  const float* W_pre = (const float*)d_in[17];
  const float* b_pre = (const float*)d_in[18];
  const float* W_out = (const float*)d_in[19];
  const float* b_out = (const float*)d_in[20];
  float* out = (float*)d_out;
  char* ws = (char*)d_ws;

  size_t off = 0;
  auto alloc = [&](size_t bytes) { void* p = ws + off; off += bytes; return p; };
  u16*   WAf  = (u16*)alloc(12582912);   // 3 planes x 2048x1024 bf16
  u16*   WBf  = (u16*)alloc(12582912);
  u16*   WPf  = (u16*)alloc(1572864);    // 3 x 512x512
  u16*   WOf  = (u16*)alloc(393216);     // 3 x 128x512
  float* GZ0  = (float*)alloc(1048576);
  float* GZ1  = (float*)alloc(1048576);
  float* gb1  = (float*)alloc(8192);
  float* zp   = (float*)alloc(262144);
  u16*   ha0  = (u16*)alloc(393216);     // 3 planes x 128x512
  u16*   ha1  = (u16*)alloc(393216);
  u16*   hb0  = (u16*)alloc(393216);
  u16*   hb1  = (u16*)alloc(393216);
  float* ca   = (float*)alloc(262144);
  float* cb   = (float*)alloc(262144);
  u16*   sbuf = (u16*)alloc(393216);
  uint32* barcnt = (uint32*)alloc(64);

  prep_hc0<<<512, 256, 0, stream>>>(z, W_l2h, b_l2h, W_l2c, b_l2c, ha0, hb0, ca, cb);
  prep_zp<<<256, 256, 0, stream>>>(z, W_zp, b_zp, zp);
  prep_gz<<<1024, 256, 0, stream>>>(zp, W_ih0, b_ih0, b_hh0, b_out, GZ0, GZ1);
  prep_waf<<<8192, 256, 0, stream>>>(W_out, W_ih0, W_hh0, WAf);
  prep_wbf<<<8192, 256, 0, stream>>>(W_ih1, W_hh1, WBf);
  prep_misc<<<2057, 256, 0, stream>>>(W_pre, W_out, b_ih1, b_hh1, WPf, WOf, gb1, sbuf, barcnt);

  // 256 blocks x 256 threads: 1 block/CU, all co-resident (56KB LDS, VGPR<=512).
  persist_k<<<256, 256, 0, stream>>>(WAf, WBf, WPf, WOf, GZ0, GZ1, gb1, ca, cb,
                                     ha0, ha1, hb0, hb1, sbuf,
                                     ln_g, ln_b, b_pre, b_out, out, barcnt);
}